// Round 13
// baseline (825.876 us; speedup 1.0000x reference)
//
#include <hip/hip_runtime.h>

// GCN: out = relu(segment_sum(feat[src], dst) @ W.T + b)
// Round 12/13 (resubmit after infra timeout; never measured): replace chain
// build (1.6M random atomicExch ~140us) + chain gather (64B nodes-line per
// edge) with bucketed LDS aggregation:
//   bucket = dst>>8 (256 nodes, agg tile = 64KB LDS).
//   K1 k_cast_bf16: feat -> bf16 (confirmed: halves feat bytes, absmax 0.125)
//   K2 k_bucket_count: per-block LDS hist -> 100k coalesced global adds
//   K3 k_scan_buckets: exclusive scan of <=1024 bucket counts (1 block)
//   K4 k_bucket_fill: LDS hist + 1 coalesced reservation per (block,bucket),
//      then LDS-cursor fill -> ebuf records (dl<<24)|src, 4B/edge
//   K5 k_agg_linear: block per bucket; waves stream 64 records (coalesced) +
//      readlane broadcast; 8 featB rows in flight; LDS atomic adds into agg
//      tile (64-lane row = 2-way bank alias = free); fused linear+bias+relu.
// Fallback to atomic-scatter path if ws too small / shapes out of range.

__device__ __forceinline__ float bcast_lane(float x, int k) {
    return __uint_as_float(__builtin_amdgcn_readlane(__float_as_uint(x), k));
}
__device__ __forceinline__ float bf16_to_f32(unsigned short h) {
    return __uint_as_float(((unsigned int)h) << 16);
}
__device__ __forceinline__ unsigned short f32_to_bf16_rne(float f) {
    unsigned int x = __float_as_uint(f);
    unsigned int r = x + 0x7fffu + ((x >> 16) & 1u);
    return (unsigned short)(r >> 16);
}

// ---------------- K1: feat -> bf16 cast ----------------

__global__ void k_cast_bf16(const float* __restrict__ feat,
                            unsigned short* __restrict__ featB, int total4) {
    int i = blockIdx.x * blockDim.x + threadIdx.x;
    if (i < total4) {
        float4 v = ((const float4*)feat)[i];
        ushort4 o;
        o.x = f32_to_bf16_rne(v.x);
        o.y = f32_to_bf16_rne(v.y);
        o.z = f32_to_bf16_rne(v.z);
        o.w = f32_to_bf16_rne(v.w);
        ((ushort4*)featB)[i] = o;
    }
}

// ---------------- K2: bucket counts (LDS hist per block) ----------------

__global__ void k_bucket_count(const int* __restrict__ dst,
                               int* __restrict__ cnt,
                               int E, int chunkE, int NB) {
    __shared__ int h[1024];
    int tid = threadIdx.x;
    h[tid] = 0;
    __syncthreads();
    int lo = blockIdx.x * chunkE;
    int hi = min(E, lo + chunkE);
    for (int i = lo + tid; i < hi; i += 1024)
        atomicAdd(&h[((unsigned)dst[i]) >> 8], 1);
    __syncthreads();
    if (tid < NB) {
        int c = h[tid];
        if (c) atomicAdd(&cnt[tid], c);   // lane-consecutive -> coalesced
    }
}

// ---------------- K3: exclusive scan (NB <= 1024, 1 block) ----------------

__global__ void k_scan_buckets(const int* __restrict__ cnt,
                               int* __restrict__ base,
                               int* __restrict__ cursor, int NB) {
    __shared__ int t[1024];
    int tid = threadIdx.x;
    int v = (tid < NB) ? cnt[tid] : 0;
    t[tid] = v;
    __syncthreads();
    for (int off = 1; off < 1024; off <<= 1) {
        int u = (tid >= off) ? t[tid - off] : 0;
        __syncthreads();
        t[tid] += u;
        __syncthreads();
    }
    if (tid < NB) {
        int excl = t[tid] - v;
        base[tid] = excl;
        cursor[tid] = excl;
    }
}

// ---------------- K4: fill ebuf (block-run reservation) ----------------

__global__ void k_bucket_fill(const int* __restrict__ src,
                              const int* __restrict__ dst,
                              int* __restrict__ cursor,
                              int* __restrict__ ebuf,
                              int E, int chunkE, int NB) {
    __shared__ int h[1024];
    int tid = threadIdx.x;
    h[tid] = 0;
    __syncthreads();
    int lo = blockIdx.x * chunkE;
    int hi = min(E, lo + chunkE);
    // pass A: count this block's edges per bucket
    for (int i = lo + tid; i < hi; i += 1024)
        atomicAdd(&h[((unsigned)dst[i]) >> 8], 1);
    __syncthreads();
    // reserve one run per (block,bucket): 1 coalesced global atomic per bin
    int run = 0;
    int c = (tid < NB) ? h[tid] : 0;
    if (c) run = atomicAdd(&cursor[tid], c);
    __syncthreads();
    h[tid] = run;          // h becomes the block-local cursor (global slots)
    __syncthreads();
    // pass B: place records
    for (int i = lo + tid; i < hi; i += 1024) {
        unsigned d = (unsigned)dst[i];
        int p = atomicAdd(&h[d >> 8], 1);
        ebuf[p] = (int)((d & 255u) << 24) | src[i];
    }
}

// ---------------- K5: per-bucket LDS aggregation + fused linear ----------------

#define AGG_WAVES 8

__global__ void __launch_bounds__(512)
k_agg_linear(const unsigned short* __restrict__ featB,
             const float* __restrict__ W,
             const float* __restrict__ b,
             const int* __restrict__ base,
             const int* __restrict__ cnt,
             const int* __restrict__ ebuf,
             float* __restrict__ out, int N) {
    __shared__ float aggS[256 * 64];   // 64 KB, exactly the static limit

    int tid  = threadIdx.x;
    int lane = tid & 63;
    int wv   = tid >> 6;               // 0..7
    int bkt  = blockIdx.x;

    // zero agg tile
    #pragma unroll
    for (int q = 0; q < 32; ++q) aggS[q * 512 + tid] = 0.0f;

    // W row 'lane' into registers; bias
    float4 w[16];
    const float4* Wv = (const float4*)(W + (lane << 6));
    #pragma unroll
    for (int q = 0; q < 16; ++q) w[q] = Wv[q];
    float bj = b[lane];

    __syncthreads();

    int ebase = base[bkt];
    int ecnt  = cnt[bkt];

    // stream this bucket's records: wave wv takes 64-record tiles
    for (int rb = wv * 64; rb < ecnt; rb += AGG_WAVES * 64) {
        int m = ecnt - rb;
        if (m > 64) m = 64;
        int rec = 0;
        if (lane < m) rec = ebuf[ebase + rb + lane];   // coalesced

        int i = 0;
        for (; i + 8 <= m; i += 8) {
            int r0 = __builtin_amdgcn_readlane(rec, i + 0);
            int r1 = __builtin_amdgcn_readlane(rec, i + 1);
            int r2 = __builtin_amdgcn_readlane(rec, i + 2);
            int r3 = __builtin_amdgcn_readlane(rec, i + 3);
            int r4 = __builtin_amdgcn_readlane(rec, i + 4);
            int r5 = __builtin_amdgcn_readlane(rec, i + 5);
            int r6 = __builtin_amdgcn_readlane(rec, i + 6);
            int r7 = __builtin_amdgcn_readlane(rec, i + 7);
            // 8 independent 128B row loads in flight
            float v0 = bf16_to_f32(featB[((r0 & 0xFFFFFF) << 6) + lane]);
            float v1 = bf16_to_f32(featB[((r1 & 0xFFFFFF) << 6) + lane]);
            float v2 = bf16_to_f32(featB[((r2 & 0xFFFFFF) << 6) + lane]);
            float v3 = bf16_to_f32(featB[((r3 & 0xFFFFFF) << 6) + lane]);
            float v4 = bf16_to_f32(featB[((r4 & 0xFFFFFF) << 6) + lane]);
            float v5 = bf16_to_f32(featB[((r5 & 0xFFFFFF) << 6) + lane]);
            float v6 = bf16_to_f32(featB[((r6 & 0xFFFFFF) << 6) + lane]);
            float v7 = bf16_to_f32(featB[((r7 & 0xFFFFFF) << 6) + lane]);
            atomicAdd(&aggS[((((unsigned)r0) >> 24) << 6) + lane], v0);
            atomicAdd(&aggS[((((unsigned)r1) >> 24) << 6) + lane], v1);
            atomicAdd(&aggS[((((unsigned)r2) >> 24) << 6) + lane], v2);
            atomicAdd(&aggS[((((unsigned)r3) >> 24) << 6) + lane], v3);
            atomicAdd(&aggS[((((unsigned)r4) >> 24) << 6) + lane], v4);
            atomicAdd(&aggS[((((unsigned)r5) >> 24) << 6) + lane], v5);
            atomicAdd(&aggS[((((unsigned)r6) >> 24) << 6) + lane], v6);
            atomicAdd(&aggS[((((unsigned)r7) >> 24) << 6) + lane], v7);
        }
        for (; i < m; ++i) {
            int r = __builtin_amdgcn_readlane(rec, i);
            atomicAdd(&aggS[((((unsigned)r) >> 24) << 6) + lane],
                      bf16_to_f32(featB[((r & 0xFFFFFF) << 6) + lane]));
        }
    }

    __syncthreads();

    // fused linear + bias + relu on the LDS tile
    int n0 = bkt << 8;
    int rows = N - n0;
    if (rows > 256) rows = 256;
    for (int r = wv; r < rows; r += AGG_WAVES) {
        float a = aggS[(r << 6) + lane];
        float acc = bj;
        #pragma unroll
        for (int k = 0; k < 64; ++k)
            acc = fmaf(bcast_lane(a, k), ((const float*)w)[k], acc);
        out[((n0 + r) << 6) + lane] = fmaxf(acc, 0.0f);
    }
}

// ---------------- fallback: atomic path ----------------

__global__ void gcn_scatter_kernel(const float* __restrict__ feat,
                                   const int* __restrict__ src,
                                   const int* __restrict__ dst,
                                   float* __restrict__ agg,
                                   int n_edges) {
    long long tid = (long long)blockIdx.x * blockDim.x + threadIdx.x;
    int e = (int)(tid >> 6);
    int f = (int)(tid & 63);
    if (e >= n_edges) return;
    atomicAdd(&agg[(long long)dst[e] * 64 + f], feat[(long long)src[e] * 64 + f]);
}

__global__ void gcn_linear_relu_kernel(const float* __restrict__ agg,
                                       const float* __restrict__ W,
                                       const float* __restrict__ b,
                                       float* __restrict__ out,
                                       int n_nodes) {
    __shared__ float Wt[64 * 65];
    __shared__ float bs[64];
    __shared__ float rows[4 * 64];
    int tid = threadIdx.x;
    #pragma unroll
    for (int it = 0; it < 16; ++it) {
        int idx = it * 256 + tid;
        Wt[(idx & 63) * 65 + (idx >> 6)] = W[idx];
    }
    if (tid < 64) bs[tid] = b[tid];
    __syncthreads();
    int li = tid >> 6, j = tid & 63;
    for (int r0 = blockIdx.x * 4; r0 < n_nodes; r0 += gridDim.x * 4) {
        int n = r0 + li;
        __syncthreads();
        if (n < n_nodes) rows[tid] = agg[(long long)n * 64 + j];
        __syncthreads();
        if (n < n_nodes) {
            float sum = bs[j];
            #pragma unroll
            for (int k = 0; k < 64; ++k)
                sum += rows[li * 64 + k] * Wt[k * 65 + j];
            out[(long long)n * 64 + j] = fmaxf(sum, 0.0f);
        }
    }
}

extern "C" void kernel_launch(void* const* d_in, const int* in_sizes, int n_in,
                              void* d_out, int out_size, void* d_ws, size_t ws_size,
                              hipStream_t stream) {
    const float* feat = (const float*)d_in[0];
    const float* W    = (const float*)d_in[1];
    const float* b    = (const float*)d_in[2];
    const int*   src  = (const int*)d_in[3];
    const int*   dst  = (const int*)d_in[4];
    float* out = (float*)d_out;

    int N = in_sizes[0] / 64;
    int E = in_sizes[3];
    int NB = (N + 255) >> 8;                      // buckets of 256 nodes

    // ws layout: featB[N*64] ushort | ebuf[E] int | cnt[NB] | base[NB] | cursor[NB]
    size_t featB_bytes = (size_t)N * 64 * sizeof(unsigned short);   // 12.8 MB
    size_t ebuf_bytes  = (size_t)E * sizeof(int);                   //  6.4 MB
    size_t meta_bytes  = (size_t)3 * NB * sizeof(int);
    size_t need = featB_bytes + ebuf_bytes + meta_bytes;

    bool shapes_ok = (NB <= 1024) && (N < (1 << 24));

    if (shapes_ok && ws_size >= need) {
        unsigned short* featB = (unsigned short*)d_ws;
        int* ebuf   = (int*)((char*)d_ws + featB_bytes);
        int* cnt    = (int*)((char*)d_ws + featB_bytes + ebuf_bytes);
        int* basep  = cnt + NB;
        int* cursor = basep + NB;

        int total4 = N * 16;
        k_cast_bf16<<<(total4 + 255) / 256, 256, 0, stream>>>(feat, featB, total4);

        hipMemsetAsync(cnt, 0, (size_t)NB * sizeof(int), stream);

        int chunkE = (E + 255) / 256;
        k_bucket_count<<<256, 1024, 0, stream>>>(dst, cnt, E, chunkE, NB);
        k_scan_buckets<<<1, 1024, 0, stream>>>(cnt, basep, cursor, NB);
        k_bucket_fill<<<256, 1024, 0, stream>>>(src, dst, cursor, ebuf, E, chunkE, NB);

        k_agg_linear<<<NB, 512, 0, stream>>>(featB, W, b, basep, cnt, ebuf, out, N);
    } else {
        // fallback: atomic scatter into out (in-place-safe linear)
        float* agg = out;
        hipMemsetAsync(agg, 0, (size_t)N * 64 * sizeof(float), stream);
        long long total = (long long)E * 64;
        gcn_scatter_kernel<<<(int)((total + 255) / 256), 256, 0, stream>>>(feat, src, dst, agg, E);
        gcn_linear_relu_kernel<<<1280, 256, 0, stream>>>(agg, W, b, out, N);
    }
}

// Round 15
// 820.323 us; speedup vs baseline: 1.0068x; 1.0068x over previous
//
#include <hip/hip_runtime.h>

// GCN: out = relu(segment_sum(feat[src], dst) @ W.T + b)
// Round 14/15 (resubmit after infra timeout; never measured): r13's
// k_agg_linear was 709us with VALU 5.4% -> diagnosed as readlane-with-
// RUNTIME-index waterfall (64-iter exec-mask loop per readlane, ~26k cy per
// 8-record batch). Fix (single variable): compile-time literal readlane
// indices via macro-expanded full-tile path (8 batches of 8); tail (<64
// records) uses __shfl (ds_bpermute, no waterfall).
// Pipeline otherwise unchanged from r13:
//   K1 cast bf16 | K2 bucket count (LDS hist) | K3 scan | K4 fill ebuf
//   K5 agg: block per 256-node bucket, 64KB LDS tile, fused linear+relu.

__device__ __forceinline__ float bcast_lane(float x, int k) {
    return __uint_as_float(__builtin_amdgcn_readlane(__float_as_uint(x), k));
}
__device__ __forceinline__ float bf16_to_f32(unsigned short h) {
    return __uint_as_float(((unsigned int)h) << 16);
}
__device__ __forceinline__ unsigned short f32_to_bf16_rne(float f) {
    unsigned int x = __float_as_uint(f);
    unsigned int r = x + 0x7fffu + ((x >> 16) & 1u);
    return (unsigned short)(r >> 16);
}

// ---------------- K1: feat -> bf16 cast ----------------

__global__ void k_cast_bf16(const float* __restrict__ feat,
                            unsigned short* __restrict__ featB, int total4) {
    int i = blockIdx.x * blockDim.x + threadIdx.x;
    if (i < total4) {
        float4 v = ((const float4*)feat)[i];
        ushort4 o;
        o.x = f32_to_bf16_rne(v.x);
        o.y = f32_to_bf16_rne(v.y);
        o.z = f32_to_bf16_rne(v.z);
        o.w = f32_to_bf16_rne(v.w);
        ((ushort4*)featB)[i] = o;
    }
}

// ---------------- K2: bucket counts (LDS hist per block) ----------------

__global__ void k_bucket_count(const int* __restrict__ dst,
                               int* __restrict__ cnt,
                               int E, int chunkE, int NB) {
    __shared__ int h[1024];
    int tid = threadIdx.x;
    h[tid] = 0;
    __syncthreads();
    int lo = blockIdx.x * chunkE;
    int hi = min(E, lo + chunkE);
    for (int i = lo + tid; i < hi; i += 1024)
        atomicAdd(&h[((unsigned)dst[i]) >> 8], 1);
    __syncthreads();
    if (tid < NB) {
        int c = h[tid];
        if (c) atomicAdd(&cnt[tid], c);   // lane-consecutive -> coalesced
    }
}

// ---------------- K3: exclusive scan (NB <= 1024, 1 block) ----------------

__global__ void k_scan_buckets(const int* __restrict__ cnt,
                               int* __restrict__ base,
                               int* __restrict__ cursor, int NB) {
    __shared__ int t[1024];
    int tid = threadIdx.x;
    int v = (tid < NB) ? cnt[tid] : 0;
    t[tid] = v;
    __syncthreads();
    for (int off = 1; off < 1024; off <<= 1) {
        int u = (tid >= off) ? t[tid - off] : 0;
        __syncthreads();
        t[tid] += u;
        __syncthreads();
    }
    if (tid < NB) {
        int excl = t[tid] - v;
        base[tid] = excl;
        cursor[tid] = excl;
    }
}

// ---------------- K4: fill ebuf (block-run reservation) ----------------

__global__ void k_bucket_fill(const int* __restrict__ src,
                              const int* __restrict__ dst,
                              int* __restrict__ cursor,
                              int* __restrict__ ebuf,
                              int E, int chunkE, int NB) {
    __shared__ int h[1024];
    int tid = threadIdx.x;
    h[tid] = 0;
    __syncthreads();
    int lo = blockIdx.x * chunkE;
    int hi = min(E, lo + chunkE);
    // pass A: count this block's edges per bucket
    for (int i = lo + tid; i < hi; i += 1024)
        atomicAdd(&h[((unsigned)dst[i]) >> 8], 1);
    __syncthreads();
    // reserve one run per (block,bucket): 1 coalesced global atomic per bin
    int run = 0;
    int c = (tid < NB) ? h[tid] : 0;
    if (c) run = atomicAdd(&cursor[tid], c);
    __syncthreads();
    h[tid] = run;          // h becomes the block-local cursor (global slots)
    __syncthreads();
    // pass B: place records
    for (int i = lo + tid; i < hi; i += 1024) {
        unsigned d = (unsigned)dst[i];
        int p = atomicAdd(&h[d >> 8], 1);
        ebuf[p] = (int)((d & 255u) << 24) | src[i];
    }
}

// ---------------- K5: per-bucket LDS aggregation + fused linear ----------------

#define AGG_WAVES 8

// 8 records with LITERAL lane indices (I is a literal: 0,8,16,...,56).
// Loads issued before atomics so 8 row-loads are in flight together.
#define BATCH8(I)                                                            \
    do {                                                                     \
        int r0 = __builtin_amdgcn_readlane(rec, (I) + 0);                    \
        int r1 = __builtin_amdgcn_readlane(rec, (I) + 1);                    \
        int r2 = __builtin_amdgcn_readlane(rec, (I) + 2);                    \
        int r3 = __builtin_amdgcn_readlane(rec, (I) + 3);                    \
        int r4 = __builtin_amdgcn_readlane(rec, (I) + 4);                    \
        int r5 = __builtin_amdgcn_readlane(rec, (I) + 5);                    \
        int r6 = __builtin_amdgcn_readlane(rec, (I) + 6);                    \
        int r7 = __builtin_amdgcn_readlane(rec, (I) + 7);                    \
        float v0 = bf16_to_f32(featB[((r0 & 0xFFFFFF) << 6) + lane]);        \
        float v1 = bf16_to_f32(featB[((r1 & 0xFFFFFF) << 6) + lane]);        \
        float v2 = bf16_to_f32(featB[((r2 & 0xFFFFFF) << 6) + lane]);        \
        float v3 = bf16_to_f32(featB[((r3 & 0xFFFFFF) << 6) + lane]);        \
        float v4 = bf16_to_f32(featB[((r4 & 0xFFFFFF) << 6) + lane]);        \
        float v5 = bf16_to_f32(featB[((r5 & 0xFFFFFF) << 6) + lane]);        \
        float v6 = bf16_to_f32(featB[((r6 & 0xFFFFFF) << 6) + lane]);        \
        float v7 = bf16_to_f32(featB[((r7 & 0xFFFFFF) << 6) + lane]);        \
        atomicAdd(&aggS[((((unsigned)r0) >> 24) << 6) + lane], v0);          \
        atomicAdd(&aggS[((((unsigned)r1) >> 24) << 6) + lane], v1);          \
        atomicAdd(&aggS[((((unsigned)r2) >> 24) << 6) + lane], v2);          \
        atomicAdd(&aggS[((((unsigned)r3) >> 24) << 6) + lane], v3);          \
        atomicAdd(&aggS[((((unsigned)r4) >> 24) << 6) + lane], v4);          \
        atomicAdd(&aggS[((((unsigned)r5) >> 24) << 6) + lane], v5);          \
        atomicAdd(&aggS[((((unsigned)r6) >> 24) << 6) + lane], v6);          \
        atomicAdd(&aggS[((((unsigned)r7) >> 24) << 6) + lane], v7);          \
    } while (0)

__global__ void __launch_bounds__(512)
k_agg_linear(const unsigned short* __restrict__ featB,
             const float* __restrict__ W,
             const float* __restrict__ b,
             const int* __restrict__ base,
             const int* __restrict__ cnt,
             const int* __restrict__ ebuf,
             float* __restrict__ out, int N) {
    __shared__ float aggS[256 * 64];   // 64 KB

    int tid  = threadIdx.x;
    int lane = tid & 63;
    int wv   = tid >> 6;               // 0..7
    int bkt  = blockIdx.x;

    // zero agg tile
    #pragma unroll
    for (int q = 0; q < 32; ++q) aggS[q * 512 + tid] = 0.0f;

    // W row 'lane' into registers; bias
    float4 w[16];
    const float4* Wv = (const float4*)(W + (lane << 6));
    #pragma unroll
    for (int q = 0; q < 16; ++q) w[q] = Wv[q];
    float bj = b[lane];

    __syncthreads();

    int ebase = base[bkt];
    int ecnt  = cnt[bkt];

    // stream this bucket's records: wave wv takes 64-record tiles
    for (int rb = wv * 64; rb < ecnt; rb += AGG_WAVES * 64) {
        int m = ecnt - rb;
        if (m > 64) m = 64;
        int rec = 0;
        if (lane < m) rec = ebuf[ebase + rb + lane];   // coalesced

        if (m == 64) {
            // full tile: literal readlane indices (no waterfall)
            BATCH8(0);  BATCH8(8);  BATCH8(16); BATCH8(24);
            BATCH8(32); BATCH8(40); BATCH8(48); BATCH8(56);
        } else {
            // tail tile: __shfl broadcast (ds_bpermute, no waterfall)
            for (int i = 0; i < m; ++i) {
                int r = __shfl(rec, i, 64);
                atomicAdd(&aggS[((((unsigned)r) >> 24) << 6) + lane],
                          bf16_to_f32(featB[((r & 0xFFFFFF) << 6) + lane]));
            }
        }
    }

    __syncthreads();

    // fused linear + bias + relu on the LDS tile
    int n0 = bkt << 8;
    int rows = N - n0;
    if (rows > 256) rows = 256;
    for (int r = wv; r < rows; r += AGG_WAVES) {
        float a = aggS[(r << 6) + lane];
        float acc = bj;
        #pragma unroll
        for (int k = 0; k < 64; ++k)
            acc = fmaf(bcast_lane(a, k), ((const float*)w)[k], acc);
        out[((n0 + r) << 6) + lane] = fmaxf(acc, 0.0f);
    }
}

// ---------------- fallback: atomic path ----------------

__global__ void gcn_scatter_kernel(const float* __restrict__ feat,
                                   const int* __restrict__ src,
                                   const int* __restrict__ dst,
                                   float* __restrict__ agg,
                                   int n_edges) {
    long long tid = (long long)blockIdx.x * blockDim.x + threadIdx.x;
    int e = (int)(tid >> 6);
    int f = (int)(tid & 63);
    if (e >= n_edges) return;
    atomicAdd(&agg[(long long)dst[e] * 64 + f], feat[(long long)src[e] * 64 + f]);
}

__global__ void gcn_linear_relu_kernel(const float* __restrict__ agg,
                                       const float* __restrict__ W,
                                       const float* __restrict__ b,
                                       float* __restrict__ out,
                                       int n_nodes) {
    __shared__ float Wt[64 * 65];
    __shared__ float bs[64];
    __shared__ float rows[4 * 64];
    int tid = threadIdx.x;
    #pragma unroll
    for (int it = 0; it < 16; ++it) {
        int idx = it * 256 + tid;
        Wt[(idx & 63) * 65 + (idx >> 6)] = W[idx];
    }
    if (tid < 64) bs[tid] = b[tid];
    __syncthreads();
    int li = tid >> 6, j = tid & 63;
    for (int r0 = blockIdx.x * 4; r0 < n_nodes; r0 += gridDim.x * 4) {
        int n = r0 + li;
        __syncthreads();
        if (n < n_nodes) rows[tid] = agg[(long long)n * 64 + j];
        __syncthreads();
        if (n < n_nodes) {
            float sum = bs[j];
            #pragma unroll
            for (int k = 0; k < 64; ++k)
                sum += rows[li * 64 + k] * Wt[k * 65 + j];
            out[(long long)n * 64 + j] = fmaxf(sum, 0.0f);
        }
    }
}

extern "C" void kernel_launch(void* const* d_in, const int* in_sizes, int n_in,
                              void* d_out, int out_size, void* d_ws, size_t ws_size,
                              hipStream_t stream) {
    const float* feat = (const float*)d_in[0];
    const float* W    = (const float*)d_in[1];
    const float* b    = (const float*)d_in[2];
    const int*   src  = (const int*)d_in[3];
    const int*   dst  = (const int*)d_in[4];
    float* out = (float*)d_out;

    int N = in_sizes[0] / 64;
    int E = in_sizes[3];
    int NB = (N + 255) >> 8;                      // buckets of 256 nodes

    // ws layout: featB[N*64] ushort | ebuf[E] int | cnt[NB] | base[NB] | cursor[NB]
    size_t featB_bytes = (size_t)N * 64 * sizeof(unsigned short);   // 12.8 MB
    size_t ebuf_bytes  = (size_t)E * sizeof(int);                   //  6.4 MB
    size_t meta_bytes  = (size_t)3 * NB * sizeof(int);
    size_t need = featB_bytes + ebuf_bytes + meta_bytes;

    bool shapes_ok = (NB <= 1024) && (N < (1 << 24));

    if (shapes_ok && ws_size >= need) {
        unsigned short* featB = (unsigned short*)d_ws;
        int* ebuf   = (int*)((char*)d_ws + featB_bytes);
        int* cnt    = (int*)((char*)d_ws + featB_bytes + ebuf_bytes);
        int* basep  = cnt + NB;
        int* cursor = basep + NB;

        int total4 = N * 16;
        k_cast_bf16<<<(total4 + 255) / 256, 256, 0, stream>>>(feat, featB, total4);

        hipMemsetAsync(cnt, 0, (size_t)NB * sizeof(int), stream);

        int chunkE = (E + 255) / 256;
        k_bucket_count<<<256, 1024, 0, stream>>>(dst, cnt, E, chunkE, NB);
        k_scan_buckets<<<1, 1024, 0, stream>>>(cnt, basep, cursor, NB);
        k_bucket_fill<<<256, 1024, 0, stream>>>(src, dst, cursor, ebuf, E, chunkE, NB);

        k_agg_linear<<<NB, 512, 0, stream>>>(featB, W, b, basep, cnt, ebuf, out, N);
    } else {
        // fallback: atomic scatter into out (in-place-safe linear)
        float* agg = out;
        hipMemsetAsync(agg, 0, (size_t)N * 64 * sizeof(float), stream);
        long long total = (long long)E * 64;
        gcn_scatter_kernel<<<(int)((total + 255) / 256), 256, 0, stream>>>(feat, src, dst, agg, E);
        gcn_linear_relu_kernel<<<1280, 256, 0, stream>>>(agg, W, b, out, N);
    }
}